// Round 9
// baseline (342.048 us; speedup 1.0000x reference)
//
#include <hip/hip_runtime.h>

#define HID 128
#define BM 32
#define BN 128
#define BKS 32
#define ALD (BKS + 8)   // LDS row stride in bf16 elems
#define SCAN_BLK 256
#define SCAN_ELEMS 1024

typedef float v4f __attribute__((ext_vector_type(4)));
typedef short v4s __attribute__((ext_vector_type(4)));
typedef short v8s __attribute__((ext_vector_type(8)));

__device__ __forceinline__ void split_bf16(float v, unsigned short& hi, unsigned short& lo) {
  const unsigned int u = __float_as_uint(v);
  hi = (unsigned short)(u >> 16);
  const float rem = v - __uint_as_float(u & 0xffff0000u);  // exact
  lo = (unsigned short)(__float_as_uint(rem) >> 16);
}

// ---- compose transposed+split B: Bt[n][k], k in [0,KT) ----
__global__ void compose_Bt(const float* __restrict__ W_lin, const float* __restrict__ W_r,
                           unsigned short* __restrict__ Bth, unsigned short* __restrict__ Btl,
                           int KT) {
  const int k = blockIdx.x;
  const int n = threadIdx.x;
  float v;
  if (k < HID) {
    v = W_lin[n * (2 * HID) + k];
  } else {
    const int rr = (k - HID) >> 7;
    const int j  = (k - HID) & (HID - 1);
    const float* wl = W_lin + n * (2 * HID) + HID;
    const float* wr = W_r + (size_t)rr * HID * HID + j;
    float acc = 0.f;
#pragma unroll 8
    for (int i2 = 0; i2 < HID; ++i2)
      acc = fmaf(wl[i2], wr[i2 * HID], acc);
    v = acc;
  }
  unsigned short hi, lo;
  split_bf16(v, hi, lo);
  Bth[(size_t)n * KT + k] = hi;
  Btl[(size_t)n * KT + k] = lo;
}

// ---- counting sort by key = dst*NUM_R + rating ----
__global__ void hist_kernel(const int* __restrict__ ed, const int* __restrict__ er,
                            int* __restrict__ hist, int NE, int NUMR) {
  const int i = blockIdx.x * blockDim.x + threadIdx.x;
  if (i < NE) atomicAdd(hist + ed[i] * NUMR + er[i], 1);
}

__global__ __launch_bounds__(SCAN_BLK)
void scan_phaseA(const int* __restrict__ cnt, int* __restrict__ partials, int n) {
  __shared__ int red[SCAN_BLK];
  const int tid = threadIdx.x;
  const int base = blockIdx.x * SCAN_ELEMS + tid * 4;
  int s = 0;
#pragma unroll
  for (int j = 0; j < 4; ++j) {
    const int i = base + j;
    if (i < n) s += cnt[i];
  }
  red[tid] = s;
  __syncthreads();
  for (int off = SCAN_BLK / 2; off > 0; off >>= 1) {
    if (tid < off) red[tid] += red[tid + off];
    __syncthreads();
  }
  if (tid == 0) partials[blockIdx.x] = red[0];
}

__global__ __launch_bounds__(1024)
void scan_phaseB(int* __restrict__ partials, int* __restrict__ offs_n, int nb) {
  __shared__ int ps[1024];
  const int tid = threadIdx.x;
  const int chunk = (nb + 1023) / 1024;
  const int b0 = tid * chunk;
  const int e0 = min(b0 + chunk, nb);
  int s = 0;
  for (int i = b0; i < e0; ++i) s += partials[i];
  ps[tid] = s;
  __syncthreads();
  for (int off = 1; off < 1024; off <<= 1) {
    const int t = (tid >= off) ? ps[tid - off] : 0;
    __syncthreads();
    ps[tid] += t;
    __syncthreads();
  }
  int run = ps[tid] - s;
  for (int i = b0; i < e0; ++i) {
    const int c = partials[i];
    partials[i] = run;
    run += c;
  }
  if (tid == 1023) offs_n[0] = ps[1023];
}

__global__ __launch_bounds__(SCAN_BLK)
void scan_phaseC(const int* __restrict__ cnt, const int* __restrict__ partials,
                 int* __restrict__ offs, int* __restrict__ cursor, int n) {
  __shared__ int tsum[SCAN_BLK];
  const int tid = threadIdx.x;
  const int base = blockIdx.x * SCAN_ELEMS + tid * 4;
  int v[4];
  int s = 0;
#pragma unroll
  for (int j = 0; j < 4; ++j) {
    const int i = base + j;
    v[j] = (i < n) ? cnt[i] : 0;
    s += v[j];
  }
  tsum[tid] = s;
  __syncthreads();
  for (int off = 1; off < SCAN_BLK; off <<= 1) {
    const int t = (tid >= off) ? tsum[tid - off] : 0;
    __syncthreads();
    tsum[tid] += t;
    __syncthreads();
  }
  int run = partials[blockIdx.x] + tsum[tid] - s;
#pragma unroll
  for (int j = 0; j < 4; ++j) {
    const int i = base + j;
    if (i < n) {
      offs[i] = run;
      cursor[i] = run;
      run += v[j];
    }
  }
}

__global__ void reorder_kernel(const int* __restrict__ es, const int* __restrict__ ed,
                               const int* __restrict__ er, int* __restrict__ cursor,
                               int* __restrict__ sorted, int NE, int NUMR) {
  const int i = blockIdx.x * blockDim.x + threadIdx.x;
  if (i < NE) {
    const int key = ed[i] * NUMR + er[i];
    const int pos = atomicAdd(cursor + key, 1);
    sorted[pos] = es[i];
  }
}

// ---- aggregation: ONE WAVE PER DST; half-wave float4; nontemporal S stores ----
template <int NR>
__global__ __launch_bounds__(256)
void aggregate_dst(const float* __restrict__ src, const int* __restrict__ sorted,
                   const int* __restrict__ offs, float* __restrict__ S, int NDST) {
  const int d = (blockIdx.x * (blockDim.x >> 6)) + (threadIdx.x >> 6);
  if (d >= NDST) return;
  const int lane = threadIdx.x & 63;
  const int half = lane >> 5;
  const int c4 = (lane & 31) * 4;

  const int base = d * NR;
  const int o0 = offs[base];
  const int oN = offs[base + NR];
  int bnd[NR - 1];
#pragma unroll
  for (int r = 0; r < NR - 1; ++r) bnd[r] = offs[base + 1 + r];
  const float inv = 1.0f / fmaxf((float)(oN - o0), 1.0f);

  v4f a[NR];
#pragma unroll
  for (int r = 0; r < NR; ++r) a[r] = (v4f){0.f, 0.f, 0.f, 0.f};

  for (int e = o0 + half; e < oN; e += 2) {
    const int s = sorted[e];
    const v4f v = *reinterpret_cast<const v4f*>(src + (size_t)s * HID + c4);
    int rloc = 0;
#pragma unroll
    for (int r = 0; r < NR - 1; ++r) rloc += (e >= bnd[r]) ? 1 : 0;
#pragma unroll
    for (int r = 0; r < NR; ++r) {
      if (rloc == r) a[r] += v;
    }
  }

#pragma unroll
  for (int r = 0; r < NR; ++r) {
    v4f t = a[r];
    v4f o;
    o[0] = __shfl_xor(t[0], 32);
    o[1] = __shfl_xor(t[1], 32);
    o[2] = __shfl_xor(t[2], 32);
    o[3] = __shfl_xor(t[3], 32);
    t += o;
    if (half == 0) {
      t *= inv;
      __builtin_nontemporal_store(t,
          reinterpret_cast<v4f*>(S + (size_t)d * (NR * HID) + r * HID + c4));
    }
  }
}

// generic fallback (one wave per segment), used only if NUM_R != 6
__global__ __launch_bounds__(256)
void aggregate_kernel(const float* __restrict__ src, const int* __restrict__ sorted,
                      const int* __restrict__ offs, float* __restrict__ S,
                      int NDST, int NUMR) {
  const int wid = (blockIdx.x * (blockDim.x >> 6)) + (threadIdx.x >> 6);
  const int lane = threadIdx.x & 63;
  if (wid >= NDST * NUMR) return;
  const int d = wid / NUMR;
  const int rloc = wid - d * NUMR;
  const int k = d * NUMR + rloc;
  const int o0 = offs[k], o1 = offs[k + 1];
  const int c0 = offs[d * NUMR], c1 = offs[d * NUMR + NUMR];
  const float inv = 1.0f / fmaxf((float)(c1 - c0), 1.0f);
  float ax = 0.f, ay = 0.f;
  for (int e = o0; e < o1; ++e) {
    const int s = sorted[e];
    const float2 v = *reinterpret_cast<const float2*>(src + (size_t)s * HID + lane * 2);
    ax += v.x; ay += v.y;
  }
  *reinterpret_cast<float2*>(S + (size_t)d * (NUMR * HID) + rloc * HID + lane * 2) =
      make_float2(ax * inv, ay * inv);
}

// ---- fused MFMA GEMM: out = relu([dstf | S] @ Bt^T + bias), K = 896 ----
// BM=32, 4 waves (2x2), wave tile 16x64 = 4 frags; reg-staged load-early/write-late.
__global__ __launch_bounds__(256)
void mfma_gemm(const float* __restrict__ dstf, const float* __restrict__ S,
               const unsigned short* __restrict__ Bth, const unsigned short* __restrict__ Btl,
               const float* __restrict__ b_lin, float* __restrict__ out,
               int M, int KT) {
  __shared__ unsigned short Ah[BM][ALD], Al[BM][ALD];
  __shared__ unsigned short Bh[BN][ALD], Bl[BN][ALD];

  const int tid = threadIdx.x;
  const int lane = tid & 63;
  const int wid = tid >> 6;
  const int wm = wid >> 1;        // 0..1 : 16-row band
  const int wn = wid & 1;         // 0..1 : 64-col band
  const int m0 = blockIdx.x * BM;
  const int l15 = lane & 15;
  const int kq = (lane >> 4) * 8;

  const int arow = tid >> 3;          // 0..31
  const int ac4 = (tid & 7) * 4;      // 0,4,..,28
  const int brow = tid >> 1;          // 0..127
  const int bc16 = (tid & 1) * 16;    // 0,16
  const int argr = m0 + arow;
  const int SSTRIDE = KT - HID;
  const int nkt = KT / BKS;

  v4f acc[4];
#pragma unroll
  for (int j = 0; j < 4; ++j) acc[j] = (v4f){0.f, 0.f, 0.f, 0.f};

  auto loadA = [&](int kg, v4f& av) {
    av = (v4f){0.f, 0.f, 0.f, 0.f};
    if (argr < M) {
      const float* p = (kg < HID)
          ? dstf + (size_t)argr * HID + kg + ac4
          : S + (size_t)argr * SSTRIDE + (kg - HID) + ac4;
      av = __builtin_nontemporal_load(reinterpret_cast<const v4f*>(p));
    }
  };
  auto loadB = [&](int kg, v8s* bh, v8s* bl) {
    const size_t gb = (size_t)brow * KT + kg + bc16;
    bh[0] = *reinterpret_cast<const v8s*>(Bth + gb);
    bh[1] = *reinterpret_cast<const v8s*>(Bth + gb + 8);
    bl[0] = *reinterpret_cast<const v8s*>(Btl + gb);
    bl[1] = *reinterpret_cast<const v8s*>(Btl + gb + 8);
  };
  auto writeLDS = [&](const v4f& av, const v8s* bh, const v8s* bl) {
    union { v4s v; unsigned short u[4]; } hh, ll;
#pragma unroll
    for (int j = 0; j < 4; ++j) split_bf16(av[j], hh.u[j], ll.u[j]);
    *reinterpret_cast<v4s*>(&Ah[arow][ac4]) = hh.v;
    *reinterpret_cast<v4s*>(&Al[arow][ac4]) = ll.v;
    *reinterpret_cast<v8s*>(&Bh[brow][bc16]) = bh[0];
    *reinterpret_cast<v8s*>(&Bh[brow][bc16 + 8]) = bh[1];
    *reinterpret_cast<v8s*>(&Bl[brow][bc16]) = bl[0];
    *reinterpret_cast<v8s*>(&Bl[brow][bc16 + 8]) = bl[1];
  };

  // prologue: stage tile 0
  {
    v4f a0; v8s bh0[2], bl0[2];
    loadA(0, a0);
    loadB(0, bh0, bl0);
    writeLDS(a0, bh0, bl0);
  }
  __syncthreads();

  for (int kt = 0; kt < nkt; ++kt) {
    const bool hasNext = (kt + 1) < nkt;
    v4f aN; v8s bhN[2], blN[2];
    if (hasNext) {              // issue next-tile loads early; latency hides under MFMA
      loadA((kt + 1) * BKS, aN);
      loadB((kt + 1) * BKS, bhN, blN);
    }

    // fragments from current LDS tile
    const int ar = wm * 16 + l15;
    const v8s afh = *reinterpret_cast<const v8s*>(&Ah[ar][kq]);
    const v8s afl = *reinterpret_cast<const v8s*>(&Al[ar][kq]);
    v8s bfh[4], bfl[4];
#pragma unroll
    for (int fn = 0; fn < 4; ++fn) {
      const int c = wn * 64 + fn * 16 + l15;
      bfh[fn] = *reinterpret_cast<const v8s*>(&Bh[c][kq]);
      bfl[fn] = *reinterpret_cast<const v8s*>(&Bl[c][kq]);
    }
#pragma unroll
    for (int fn = 0; fn < 4; ++fn) {
      acc[fn] = __builtin_amdgcn_mfma_f32_16x16x32_bf16(afh, bfh[fn], acc[fn], 0, 0, 0);
      acc[fn] = __builtin_amdgcn_mfma_f32_16x16x32_bf16(afh, bfl[fn], acc[fn], 0, 0, 0);
      acc[fn] = __builtin_amdgcn_mfma_f32_16x16x32_bf16(afl, bfh[fn], acc[fn], 0, 0, 0);
    }
    __syncthreads();           // all waves done reading tile kt
    if (hasNext) {
      writeLDS(aN, bhN, blN);  // write-late: vmcnt waits land here
      __syncthreads();
    }
  }

  // epilogue: bias + relu; C/D map: col=lane&15, row=(lane>>4)*4+reg
#pragma unroll
  for (int fn = 0; fn < 4; ++fn) {
    const int cn = wn * 64 + fn * 16 + l15;
    const float bias = b_lin[cn];
    const int row0 = m0 + wm * 16 + (lane >> 4) * 4;
#pragma unroll
    for (int r = 0; r < 4; ++r) {
      const int rg = row0 + r;
      if (rg < M) out[(size_t)rg * HID + cn] = fmaxf(acc[fn][r] + bias, 0.f);
    }
  }
}

extern "C" void kernel_launch(void* const* d_in, const int* in_sizes, int n_in,
                              void* d_out, int out_size, void* d_ws, size_t ws_size,
                              hipStream_t stream) {
  const float* src   = (const float*)d_in[0];
  const float* dstf  = (const float*)d_in[1];
  const float* W_r   = (const float*)d_in[2];
  const float* W_lin = (const float*)d_in[3];
  const float* b_lin = (const float*)d_in[4];
  const int* e_src   = (const int*)d_in[5];
  const int* e_dst   = (const int*)d_in[6];
  const int* e_rat   = (const int*)d_in[7];

  const int N_DST = in_sizes[1] / HID;
  const int NUM_R = in_sizes[2] / (HID * HID);
  const int NE = in_sizes[5];
  const int KT = HID + NUM_R * HID;     // 896
  const int NKEY = N_DST * NUM_R;       // 300000
  const int NB = (NKEY + SCAN_ELEMS - 1) / SCAN_ELEMS;

  const size_t S_b      = (size_t)N_DST * (NUM_R * HID) * sizeof(float);  // 153.6 MB
  const size_t hist_b   = (size_t)NKEY * sizeof(int);
  const size_t offs_b   = (size_t)(NKEY + 1) * sizeof(int);
  const size_t cursor_b = (size_t)NKEY * sizeof(int);
  const size_t sorted_b = (size_t)NE * sizeof(int);
  const size_t part_b   = (size_t)NB * sizeof(int);
  const size_t Bt_b     = (size_t)HID * KT * sizeof(unsigned short);
  const size_t need = S_b + hist_b + offs_b + cursor_b + sorted_b + part_b + 2 * Bt_b + 4096;
  if (ws_size < need) return;  // fail loudly in verification

  char* p = (char*)d_ws;
  float* S = (float*)p;            p += (S_b + 255) & ~(size_t)255;
  int* hist = (int*)p;             p += (hist_b + 255) & ~(size_t)255;
  int* offs = (int*)p;             p += (offs_b + 255) & ~(size_t)255;
  int* cursor = (int*)p;           p += (cursor_b + 255) & ~(size_t)255;
  int* sorted = (int*)p;           p += (sorted_b + 255) & ~(size_t)255;
  int* partials = (int*)p;         p += (part_b + 255) & ~(size_t)255;
  unsigned short* Bth = (unsigned short*)p;  p += (Bt_b + 255) & ~(size_t)255;
  unsigned short* Btl = (unsigned short*)p;

  compose_Bt<<<KT, HID, 0, stream>>>(W_lin, W_r, Bth, Btl, KT);
  hipMemsetAsync(hist, 0, hist_b, stream);
  hist_kernel<<<(NE + 255) / 256, 256, 0, stream>>>(e_dst, e_rat, hist, NE, NUM_R);
  scan_phaseA<<<NB, SCAN_BLK, 0, stream>>>(hist, partials, NKEY);
  scan_phaseB<<<1, 1024, 0, stream>>>(partials, offs + NKEY, NB);
  scan_phaseC<<<NB, SCAN_BLK, 0, stream>>>(hist, partials, offs, cursor, NKEY);
  reorder_kernel<<<(NE + 255) / 256, 256, 0, stream>>>(e_src, e_dst, e_rat, cursor,
                                                       sorted, NE, NUM_R);
  if (NUM_R == 6) {
    aggregate_dst<6><<<(N_DST + 3) / 4, 256, 0, stream>>>(src, sorted, offs, S, N_DST);
  } else {
    const int nwaves = N_DST * NUM_R;
    aggregate_kernel<<<(nwaves + 3) / 4, 256, 0, stream>>>(src, sorted, offs, S,
                                                           N_DST, NUM_R);
  }
  const int mb = (N_DST + BM - 1) / BM;
  mfma_gemm<<<mb, 256, 0, stream>>>(dstf, S, Bth, Btl, b_lin, (float*)d_out,
                                    N_DST, KT);
}

// Round 11
// 300.514 us; speedup vs baseline: 1.1382x; 1.1382x over previous
//
#include <hip/hip_runtime.h>

#define HID 128
#define BM 128
#define BN 128
#define BKS 32
#define ALD 36          // LDS row stride in shorts (72B: odd multiple of 8B -> uniform banks)
#define SCAN_BLK 256
#define SCAN_ELEMS 1024

typedef float v4f __attribute__((ext_vector_type(4)));
typedef short v4s __attribute__((ext_vector_type(4)));
typedef short v8s __attribute__((ext_vector_type(8)));

__device__ __forceinline__ void split_bf16(float v, unsigned short& hi, unsigned short& lo) {
  const unsigned int u = __float_as_uint(v);
  hi = (unsigned short)(u >> 16);
  const float rem = v - __uint_as_float(u & 0xffff0000u);  // exact
  lo = (unsigned short)(__float_as_uint(rem) >> 16);
}

// ---- compose transposed+split B: Bt[n][k], k in [0,KT) ----
__global__ void compose_Bt(const float* __restrict__ W_lin, const float* __restrict__ W_r,
                           unsigned short* __restrict__ Bth, unsigned short* __restrict__ Btl,
                           int KT) {
  const int k = blockIdx.x;
  const int n = threadIdx.x;
  float v;
  if (k < HID) {
    v = W_lin[n * (2 * HID) + k];
  } else {
    const int rr = (k - HID) >> 7;
    const int j  = (k - HID) & (HID - 1);
    const float* wl = W_lin + n * (2 * HID) + HID;
    const float* wr = W_r + (size_t)rr * HID * HID + j;
    float acc = 0.f;
#pragma unroll 8
    for (int i2 = 0; i2 < HID; ++i2)
      acc = fmaf(wl[i2], wr[i2 * HID], acc);
    v = acc;
  }
  unsigned short hi, lo;
  split_bf16(v, hi, lo);
  Bth[(size_t)n * KT + k] = hi;
  Btl[(size_t)n * KT + k] = lo;
}

// ---- counting sort by key = dst*NUM_R + rating ----
__global__ void hist_kernel(const int* __restrict__ ed, const int* __restrict__ er,
                            int* __restrict__ hist, int NE, int NUMR) {
  const int i = blockIdx.x * blockDim.x + threadIdx.x;
  if (i < NE) atomicAdd(hist + ed[i] * NUMR + er[i], 1);
}

__global__ __launch_bounds__(SCAN_BLK)
void scan_phaseA(const int* __restrict__ cnt, int* __restrict__ partials, int n) {
  __shared__ int red[SCAN_BLK];
  const int tid = threadIdx.x;
  const int base = blockIdx.x * SCAN_ELEMS + tid * 4;
  int s = 0;
#pragma unroll
  for (int j = 0; j < 4; ++j) {
    const int i = base + j;
    if (i < n) s += cnt[i];
  }
  red[tid] = s;
  __syncthreads();
  for (int off = SCAN_BLK / 2; off > 0; off >>= 1) {
    if (tid < off) red[tid] += red[tid + off];
    __syncthreads();
  }
  if (tid == 0) partials[blockIdx.x] = red[0];
}

__global__ __launch_bounds__(1024)
void scan_phaseB(int* __restrict__ partials, int* __restrict__ offs_n, int nb) {
  __shared__ int ps[1024];
  const int tid = threadIdx.x;
  const int chunk = (nb + 1023) / 1024;
  const int b0 = tid * chunk;
  const int e0 = min(b0 + chunk, nb);
  int s = 0;
  for (int i = b0; i < e0; ++i) s += partials[i];
  ps[tid] = s;
  __syncthreads();
  for (int off = 1; off < 1024; off <<= 1) {
    const int t = (tid >= off) ? ps[tid - off] : 0;
    __syncthreads();
    ps[tid] += t;
    __syncthreads();
  }
  int run = ps[tid] - s;
  for (int i = b0; i < e0; ++i) {
    const int c = partials[i];
    partials[i] = run;
    run += c;
  }
  if (tid == 1023) offs_n[0] = ps[1023];
}

__global__ __launch_bounds__(SCAN_BLK)
void scan_phaseC(const int* __restrict__ cnt, const int* __restrict__ partials,
                 int* __restrict__ offs, int* __restrict__ cursor, int n) {
  __shared__ int tsum[SCAN_BLK];
  const int tid = threadIdx.x;
  const int base = blockIdx.x * SCAN_ELEMS + tid * 4;
  int v[4];
  int s = 0;
#pragma unroll
  for (int j = 0; j < 4; ++j) {
    const int i = base + j;
    v[j] = (i < n) ? cnt[i] : 0;
    s += v[j];
  }
  tsum[tid] = s;
  __syncthreads();
  for (int off = 1; off < SCAN_BLK; off <<= 1) {
    const int t = (tid >= off) ? tsum[tid - off] : 0;
    __syncthreads();
    tsum[tid] += t;
    __syncthreads();
  }
  int run = partials[blockIdx.x] + tsum[tid] - s;
#pragma unroll
  for (int j = 0; j < 4; ++j) {
    const int i = base + j;
    if (i < n) {
      offs[i] = run;
      cursor[i] = run;
      run += v[j];
    }
  }
}

__global__ void reorder_kernel(const int* __restrict__ es, const int* __restrict__ ed,
                               const int* __restrict__ er, int* __restrict__ cursor,
                               int* __restrict__ sorted, int NE, int NUMR) {
  const int i = blockIdx.x * blockDim.x + threadIdx.x;
  if (i < NE) {
    const int key = ed[i] * NUMR + er[i];
    const int pos = atomicAdd(cursor + key, 1);
    sorted[pos] = es[i];
  }
}

// ---- aggregation: ONE WAVE PER DST; half-wave float4; nontemporal S stores ----
template <int NR>
__global__ __launch_bounds__(256)
void aggregate_dst(const float* __restrict__ src, const int* __restrict__ sorted,
                   const int* __restrict__ offs, float* __restrict__ S, int NDST) {
  const int d = (blockIdx.x * (blockDim.x >> 6)) + (threadIdx.x >> 6);
  if (d >= NDST) return;
  const int lane = threadIdx.x & 63;
  const int half = lane >> 5;
  const int c4 = (lane & 31) * 4;

  const int base = d * NR;
  const int o0 = offs[base];
  const int oN = offs[base + NR];
  int bnd[NR - 1];
#pragma unroll
  for (int r = 0; r < NR - 1; ++r) bnd[r] = offs[base + 1 + r];
  const float inv = 1.0f / fmaxf((float)(oN - o0), 1.0f);

  v4f a[NR];
#pragma unroll
  for (int r = 0; r < NR; ++r) a[r] = (v4f){0.f, 0.f, 0.f, 0.f};

  for (int e = o0 + half; e < oN; e += 2) {
    const int s = sorted[e];
    const v4f v = *reinterpret_cast<const v4f*>(src + (size_t)s * HID + c4);
    int rloc = 0;
#pragma unroll
    for (int r = 0; r < NR - 1; ++r) rloc += (e >= bnd[r]) ? 1 : 0;
#pragma unroll
    for (int r = 0; r < NR; ++r) {
      if (rloc == r) a[r] += v;
    }
  }

#pragma unroll
  for (int r = 0; r < NR; ++r) {
    v4f t = a[r];
    v4f o;
    o[0] = __shfl_xor(t[0], 32);
    o[1] = __shfl_xor(t[1], 32);
    o[2] = __shfl_xor(t[2], 32);
    o[3] = __shfl_xor(t[3], 32);
    t += o;
    if (half == 0) {
      t *= inv;
      __builtin_nontemporal_store(t,
          reinterpret_cast<v4f*>(S + (size_t)d * (NR * HID) + r * HID + c4));
    }
  }
}

// generic fallback (one wave per segment), used only if NUM_R != 6
__global__ __launch_bounds__(256)
void aggregate_kernel(const float* __restrict__ src, const int* __restrict__ sorted,
                      const int* __restrict__ offs, float* __restrict__ S,
                      int NDST, int NUMR) {
  const int wid = (blockIdx.x * (blockDim.x >> 6)) + (threadIdx.x >> 6);
  const int lane = threadIdx.x & 63;
  if (wid >= NDST * NUMR) return;
  const int d = wid / NUMR;
  const int rloc = wid - d * NUMR;
  const int k = d * NUMR + rloc;
  const int o0 = offs[k], o1 = offs[k + 1];
  const int c0 = offs[d * NUMR], c1 = offs[d * NUMR + NUMR];
  const float inv = 1.0f / fmaxf((float)(c1 - c0), 1.0f);
  float ax = 0.f, ay = 0.f;
  for (int e = o0; e < o1; ++e) {
    const int s = sorted[e];
    const float2 v = *reinterpret_cast<const float2*>(src + (size_t)s * HID + lane * 2);
    ax += v.x; ay += v.y;
  }
  *reinterpret_cast<float2*>(S + (size_t)d * (NUMR * HID) + rloc * HID + lane * 2) =
      make_float2(ax * inv, ay * inv);
}

// ---- fused MFMA GEMM v3: out = relu([dstf | S] @ Bt^T + bias), K = 896 ----
// 512 threads, BM=128, 8 waves (4x2), wave tile 32x64 -> 24 MFMA/iter.
// Double-buffered LDS, ONE barrier per iteration; loads issued a full phase early.
__global__ __launch_bounds__(512)
void mfma_gemm(const float* __restrict__ dstf, const float* __restrict__ S,
               const unsigned short* __restrict__ Bth, const unsigned short* __restrict__ Btl,
               const float* __restrict__ b_lin, float* __restrict__ out,
               int M, int KT) {
  __shared__ unsigned short Ah[2][BM][ALD], Al[2][BM][ALD];
  __shared__ unsigned short Bh[2][BN][ALD], Bl[2][BN][ALD];

  const int tid = threadIdx.x;
  const int lane = tid & 63;
  const int wid = tid >> 6;
  const int wm = wid >> 1;        // 0..3 : 32-row band
  const int wn = wid & 1;         // 0..1 : 64-col band
  const int m0 = blockIdx.x * BM;
  const int l15 = lane & 15;
  const int kq = (lane >> 4) * 8;

  const int arow = tid >> 2;          // 0..127
  const int ac8 = (tid & 3) * 8;      // 0,8,16,24
  const int argr = m0 + arow;
  const int SSTRIDE = KT - HID;
  const int nkt = KT / BKS;           // 28

  v4f acc[2][4];
#pragma unroll
  for (int i = 0; i < 2; ++i)
#pragma unroll
    for (int j = 0; j < 4; ++j) acc[i][j] = (v4f){0.f, 0.f, 0.f, 0.f};

  float aReg[8];
  v8s bhReg, blReg;

  auto loadTile = [&](int kg) {
    // A: 8 f32 per thread (coalesced 32B per 4 threads within a row)
    v4f v0 = (v4f){0.f, 0.f, 0.f, 0.f};
    v4f v1 = (v4f){0.f, 0.f, 0.f, 0.f};
    if (argr < M) {
      const float* p = (kg < HID)
          ? dstf + (size_t)argr * HID + kg + ac8
          : S + (size_t)argr * SSTRIDE + (kg - HID) + ac8;
      v0 = __builtin_nontemporal_load(reinterpret_cast<const v4f*>(p));
      v1 = __builtin_nontemporal_load(reinterpret_cast<const v4f*>(p + 4));
    }
    aReg[0] = v0[0]; aReg[1] = v0[1]; aReg[2] = v0[2]; aReg[3] = v0[3];
    aReg[4] = v1[0]; aReg[5] = v1[1]; aReg[6] = v1[2]; aReg[7] = v1[3];
    // B: 8 shorts per plane per thread (n = arow, kc = ac8)
    const size_t gb = (size_t)arow * KT + kg + ac8;
    bhReg = *reinterpret_cast<const v8s*>(Bth + gb);
    blReg = *reinterpret_cast<const v8s*>(Btl + gb);
  };

  auto writeTile = [&](int p) {
    union { v4s v[2]; unsigned short u[8]; } hh, ll;
#pragma unroll
    for (int j = 0; j < 8; ++j) split_bf16(aReg[j], hh.u[j], ll.u[j]);
    *reinterpret_cast<v4s*>(&Ah[p][arow][ac8])     = hh.v[0];
    *reinterpret_cast<v4s*>(&Ah[p][arow][ac8 + 4]) = hh.v[1];
    *reinterpret_cast<v4s*>(&Al[p][arow][ac8])     = ll.v[0];
    *reinterpret_cast<v4s*>(&Al[p][arow][ac8 + 4]) = ll.v[1];
    union { v8s v; v4s h[2]; } bu;
    bu.v = bhReg;
    *reinterpret_cast<v4s*>(&Bh[p][arow][ac8])     = bu.h[0];
    *reinterpret_cast<v4s*>(&Bh[p][arow][ac8 + 4]) = bu.h[1];
    bu.v = blReg;
    *reinterpret_cast<v4s*>(&Bl[p][arow][ac8])     = bu.h[0];
    *reinterpret_cast<v4s*>(&Bl[p][arow][ac8 + 4]) = bu.h[1];
  };

  // prologue: stage tile 0 into buffer 0
  loadTile(0);
  writeTile(0);
  __syncthreads();

  int p = 0;
  for (int kt = 0; kt < nkt; ++kt) {
    const bool hasNext = (kt + 1) < nkt;
    if (hasNext) loadTile((kt + 1) * BKS);   // in flight across the MFMA phase

    // fragments from buffer p (8B reads, uniform bank spread at stride 36)
    union { v8s v; v4s h[2]; } afh[2], afl[2], bfh[4], bfl[4];
#pragma unroll
    for (int fm = 0; fm < 2; ++fm) {
      const int r = wm * 32 + fm * 16 + l15;
      afh[fm].h[0] = *reinterpret_cast<const v4s*>(&Ah[p][r][kq]);
      afh[fm].h[1] = *reinterpret_cast<const v4s*>(&Ah[p][r][kq + 4]);
      afl[fm].h[0] = *reinterpret_cast<const v4s*>(&Al[p][r][kq]);
      afl[fm].h[1] = *reinterpret_cast<const v4s*>(&Al[p][r][kq + 4]);
    }
#pragma unroll
    for (int fn = 0; fn < 4; ++fn) {
      const int c = wn * 64 + fn * 16 + l15;
      bfh[fn].h[0] = *reinterpret_cast<const v4s*>(&Bh[p][c][kq]);
      bfh[fn].h[1] = *reinterpret_cast<const v4s*>(&Bh[p][c][kq + 4]);
      bfl[fn].h[0] = *reinterpret_cast<const v4s*>(&Bl[p][c][kq]);
      bfl[fn].h[1] = *reinterpret_cast<const v4s*>(&Bl[p][c][kq + 4]);
    }
#pragma unroll
    for (int fm = 0; fm < 2; ++fm)
#pragma unroll
      for (int fn = 0; fn < 4; ++fn) {
        acc[fm][fn] = __builtin_amdgcn_mfma_f32_16x16x32_bf16(afh[fm].v, bfh[fn].v, acc[fm][fn], 0, 0, 0);
        acc[fm][fn] = __builtin_amdgcn_mfma_f32_16x16x32_bf16(afh[fm].v, bfl[fn].v, acc[fm][fn], 0, 0, 0);
        acc[fm][fn] = __builtin_amdgcn_mfma_f32_16x16x32_bf16(afl[fm].v, bfh[fn].v, acc[fm][fn], 0, 0, 0);
      }

    if (hasNext) writeTile(p ^ 1);   // different buffer: overlaps others' reads of p
    __syncthreads();                 // single barrier per iteration
    p ^= 1;
  }

  // epilogue: bias + relu; C/D map: col=lane&15, row=(lane>>4)*4+reg
#pragma unroll
  for (int fn = 0; fn < 4; ++fn) {
    const int cn = wn * 64 + fn * 16 + l15;
    const float bias = b_lin[cn];
#pragma unroll
    for (int fm = 0; fm < 2; ++fm) {
      const int row0 = m0 + wm * 32 + fm * 16 + (lane >> 4) * 4;
#pragma unroll
      for (int r = 0; r < 4; ++r) {
        const int rg = row0 + r;
        if (rg < M) out[(size_t)rg * HID + cn] = fmaxf(acc[fm][fn][r] + bias, 0.f);
      }
    }
  }
}

extern "C" void kernel_launch(void* const* d_in, const int* in_sizes, int n_in,
                              void* d_out, int out_size, void* d_ws, size_t ws_size,
                              hipStream_t stream) {
  const float* src   = (const float*)d_in[0];
  const float* dstf  = (const float*)d_in[1];
  const float* W_r   = (const float*)d_in[2];
  const float* W_lin = (const float*)d_in[3];
  const float* b_lin = (const float*)d_in[4];
  const int* e_src   = (const int*)d_in[5];
  const int* e_dst   = (const int*)d_in[6];
  const int* e_rat   = (const int*)d_in[7];

  const int N_DST = in_sizes[1] / HID;
  const int NUM_R = in_sizes[2] / (HID * HID);
  const int NE = in_sizes[5];
  const int KT = HID + NUM_R * HID;     // 896
  const int NKEY = N_DST * NUM_R;       // 300000
  const int NB = (NKEY + SCAN_ELEMS - 1) / SCAN_ELEMS;

  const size_t S_b      = (size_t)N_DST * (NUM_R * HID) * sizeof(float);  // 153.6 MB
  const size_t hist_b   = (size_t)NKEY * sizeof(int);
  const size_t offs_b   = (size_t)(NKEY + 1) * sizeof(int);
  const size_t cursor_b = (size_t)NKEY * sizeof(int);
  const size_t sorted_b = (size_t)NE * sizeof(int);
  const size_t part_b   = (size_t)NB * sizeof(int);
  const size_t Bt_b     = (size_t)HID * KT * sizeof(unsigned short);
  const size_t need = S_b + hist_b + offs_b + cursor_b + sorted_b + part_b + 2 * Bt_b + 4096;
  if (ws_size < need) return;  // fail loudly in verification

  char* p = (char*)d_ws;
  float* S = (float*)p;            p += (S_b + 255) & ~(size_t)255;
  int* hist = (int*)p;             p += (hist_b + 255) & ~(size_t)255;
  int* offs = (int*)p;             p += (offs_b + 255) & ~(size_t)255;
  int* cursor = (int*)p;           p += (cursor_b + 255) & ~(size_t)255;
  int* sorted = (int*)p;           p += (sorted_b + 255) & ~(size_t)255;
  int* partials = (int*)p;         p += (part_b + 255) & ~(size_t)255;
  unsigned short* Bth = (unsigned short*)p;  p += (Bt_b + 255) & ~(size_t)255;
  unsigned short* Btl = (unsigned short*)p;

  compose_Bt<<<KT, HID, 0, stream>>>(W_lin, W_r, Bth, Btl, KT);
  hipMemsetAsync(hist, 0, hist_b, stream);
  hist_kernel<<<(NE + 255) / 256, 256, 0, stream>>>(e_dst, e_rat, hist, NE, NUM_R);
  scan_phaseA<<<NB, SCAN_BLK, 0, stream>>>(hist, partials, NKEY);
  scan_phaseB<<<1, 1024, 0, stream>>>(partials, offs + NKEY, NB);
  scan_phaseC<<<NB, SCAN_BLK, 0, stream>>>(hist, partials, offs, cursor, NKEY);
  reorder_kernel<<<(NE + 255) / 256, 256, 0, stream>>>(e_src, e_dst, e_rat, cursor,
                                                       sorted, NE, NUM_R);
  if (NUM_R == 6) {
    aggregate_dst<6><<<(N_DST + 3) / 4, 256, 0, stream>>>(src, sorted, offs, S, N_DST);
  } else {
    const int nwaves = N_DST * NUM_R;
    aggregate_kernel<<<(nwaves + 3) / 4, 256, 0, stream>>>(src, sorted, offs, S,
                                                           N_DST, NUM_R);
  }
  const int mb = (N_DST + BM - 1) / BM;
  mfma_gemm<<<mb, 512, 0, stream>>>(dstf, S, Bth, Btl, b_lin, (float*)d_out,
                                    N_DST, KT);
}